// Round 2
// baseline (778.529 us; speedup 1.0000x reference)
//
#include <hip/hip_runtime.h>

// DecoderGRU: h_{t+1} = GRUCell(h_t, h_t), 64 steps, out[b][t][h] = h_{t+1}.
// Combined-gate trick: r,z gates use (W_ih + W_hh); n gate keeps i_n, h_n
// separate -> one [512,1024]x[1024,4096] bf16 MFMA GEMM per step, fused with
// the elementwise GRU update.

typedef float  f32x4 __attribute__((ext_vector_type(4)));
typedef __bf16 bf16x8 __attribute__((ext_vector_type(8)));
typedef unsigned short u16x8 __attribute__((ext_vector_type(8)));

#define GPTR(p) ((const __attribute__((address_space(1))) unsigned int*)(p))
#define LPTR(p) ((__attribute__((address_space(3))) unsigned int*)(p))

__device__ __forceinline__ unsigned short f2bf(float f){
  unsigned int u = __builtin_bit_cast(unsigned int, f);
  u = (u + 0x7FFFu + ((u >> 16) & 1u)) >> 16;
  return (unsigned short)u;
}

// ---------------------------------------------------------------------------
// Prologue 1: combined, transposed, swizzled bf16 weights.
// WB layout: colIdx = (c>>5)*128 + gate*32 + (c&31), element (colIdx,k) at
// byte colIdx*2048 + ((2k) ^ ((colIdx&7)<<4)).  gates: 0=r(ih+hh) 1=z(ih+hh)
// 2=i_n(ih) 3=h_n(hh).  B[k][col] = W[col][k]  (gemm is h @ W^T).
// ---------------------------------------------------------------------------
extern "C" __global__ void gru_weights(const float* __restrict__ wih,
                                       const float* __restrict__ whh,
                                       char* __restrict__ WB){
  int gt  = blockIdx.x * 256 + threadIdx.x;   // 524288 threads total
  int k0  = (gt & 127) << 3;                  // 8 k's per thread
  int gid = gt >> 7;                          // (gate, col)
  int g   = gid >> 10, c = gid & 1023;
  int srow = (g < 2) ? g * 1024 + c : 2048 + c;
  const float* pa = ((g == 3) ? whh : wih) + srow * 1024 + k0;
  f32x4 v0 = ((const f32x4*)pa)[0];
  f32x4 v1 = ((const f32x4*)pa)[1];
  if (g < 2){
    const float* pb = whh + srow * 1024 + k0;
    v0 += ((const f32x4*)pb)[0];
    v1 += ((const f32x4*)pb)[1];
  }
  u16x8 o;
  #pragma unroll
  for (int e = 0; e < 4; e++){ o[e] = f2bf(v0[e]); o[4 + e] = f2bf(v1[e]); }
  int cc = c & 31;
  int colIdx = (c >> 5) * 128 + g * 32 + cc;
  int addr = colIdx * 2048 + ((k0 * 2) ^ ((cc & 7) << 4));
  *(u16x8*)(WB + addr) = o;
}

// ---------------------------------------------------------------------------
// Prologue 2: h fp32 copy, swizzled bf16 A0, combined biases [4][1024].
// ---------------------------------------------------------------------------
extern "C" __global__ void gru_init(const float* __restrict__ hidden,
                                    const float* __restrict__ bih,
                                    const float* __restrict__ bhh,
                                    float* __restrict__ hws,
                                    char* __restrict__ A0,
                                    float* __restrict__ bias){
  int gt = blockIdx.x * 256 + threadIdx.x;    // 65536 threads, 8 elems each
  int e0 = gt * 8;
  int r  = e0 >> 10, c0 = e0 & 1023;
  f32x4 v0 = ((const f32x4*)(hidden + e0))[0];
  f32x4 v1 = ((const f32x4*)(hidden + e0))[1];
  ((f32x4*)(hws + e0))[0] = v0;
  ((f32x4*)(hws + e0))[1] = v1;
  u16x8 o;
  #pragma unroll
  for (int e = 0; e < 4; e++){ o[e] = f2bf(v0[e]); o[4 + e] = f2bf(v1[e]); }
  *(u16x8*)(A0 + r * 2048 + ((c0 * 2) ^ ((r & 7) << 4))) = o;
  if (blockIdx.x < 16){
    int bi = blockIdx.x * 256 + threadIdx.x;  // 4096 bias entries
    int g = bi >> 10, c = bi & 1023;
    float v = (g == 0) ? bih[c]        + bhh[c]
            : (g == 1) ? bih[1024 + c] + bhh[1024 + c]
            : (g == 2) ? bih[2048 + c] : bhh[2048 + c];
    bias[bi] = v;
  }
}

// ---------------------------------------------------------------------------
// Step kernel: grid 256 (8 row-blocks x 32 col-blocks, XCD-grouped by col),
// block 256 (4 waves).  Tile 64 rows x 128 gate-cols, K=1024, BK=64 chunks,
// double-buffered global_load_lds staging.  Wave w owns gate w (Nf=2,Mf=4).
// LDS map: A buffers at 0 / 8192, B buffers at 16384 / 32768.
// ---------------------------------------------------------------------------
extern "C" __global__ void __launch_bounds__(256, 1)
gru_step(const char* __restrict__ Acur, char* __restrict__ Anext,
         float* __restrict__ hws, const char* __restrict__ WB,
         const float* __restrict__ bias, float* __restrict__ out, int t)
{
  __shared__ __align__(16) char lds[49152];
  const int tid = threadIdx.x;
  const int wv = tid >> 6, ln = tid & 63;
  const int bid = blockIdx.x;
  // XCD grouping: blocks with bid%8==x get col-blocks {4x..4x+3}, all rows.
  const int j  = (bid & 7) * 4 + ((bid >> 3) & 3);
  const int rb = bid >> 5;

  const f32x4 zero = {0.f, 0.f, 0.f, 0.f};
  f32x4 acc[4][2];
  #pragma unroll
  for (int m = 0; m < 4; m++)
    #pragma unroll
    for (int n = 0; n < 2; n++) acc[m][n] = zero;

  const int lrow = ln & 15, lq = ln >> 4;
  const int abase = rb * 64 * 2048;
  const int bbase = j * 128 * 2048;

  // stage chunk 0 into buffer 0
  #pragma unroll
  for (int c = 0; c < 2; c++){
    int o = c * 4096 + wv * 1024 + ln * 16;
    __builtin_amdgcn_global_load_lds(GPTR(Acur + abase + (o >> 7) * 2048 + (o & 127)),
                                     LPTR(lds + c * 4096 + wv * 1024), 16, 0, 0);
  }
  #pragma unroll
  for (int c = 0; c < 4; c++){
    int o = c * 4096 + wv * 1024 + ln * 16;
    __builtin_amdgcn_global_load_lds(GPTR(WB + bbase + (o >> 7) * 2048 + (o & 127)),
                                     LPTR(lds + 16384 + c * 4096 + wv * 1024), 16, 0, 0);
  }
  __syncthreads();

  for (int kk = 0; kk < 16; kk++){
    if (kk < 15){
      const int nb = (kk + 1) & 1;
      const int ko = (kk + 1) * 128;
      #pragma unroll
      for (int c = 0; c < 2; c++){
        int o = c * 4096 + wv * 1024 + ln * 16;
        __builtin_amdgcn_global_load_lds(GPTR(Acur + abase + (o >> 7) * 2048 + ko + (o & 127)),
                                         LPTR(lds + nb * 8192 + c * 4096 + wv * 1024), 16, 0, 0);
      }
      #pragma unroll
      for (int c = 0; c < 4; c++){
        int o = c * 4096 + wv * 1024 + ln * 16;
        __builtin_amdgcn_global_load_lds(GPTR(WB + bbase + (o >> 7) * 2048 + ko + (o & 127)),
                                         LPTR(lds + 16384 + nb * 16384 + c * 4096 + wv * 1024), 16, 0, 0);
      }
    }
    const int cb = kk & 1;
    #pragma unroll
    for (int kk2 = 0; kk2 < 2; kk2++){
      const int kb = kk2 * 64 + lq * 16;
      bf16x8 a[4], b[2];
      #pragma unroll
      for (int m = 0; m < 4; m++){
        int r = m * 16 + lrow;
        a[m] = *(const bf16x8*)(lds + cb * 8192 + r * 128 + (kb ^ ((r & 7) << 4)));
      }
      #pragma unroll
      for (int n = 0; n < 2; n++){
        int ccol = wv * 32 + n * 16 + lrow;
        b[n] = *(const bf16x8*)(lds + 16384 + cb * 16384 + ccol * 128 + (kb ^ ((ccol & 7) << 4)));
      }
      #pragma unroll
      for (int m = 0; m < 4; m++)
        #pragma unroll
        for (int n = 0; n < 2; n++)
          acc[m][n] = __builtin_amdgcn_mfma_f32_16x16x32_bf16(a[m], b[n], acc[m][n], 0, 0, 0);
    }
    __syncthreads();
  }

  // ---- epilogue: cross-wave gate exchange via LDS -------------------------
  // G[gate][row 64][36 floats] (pad 36 to spread banks), gate stride 2304.
  float* G = (float*)lds;
  const float bv0 = bias[wv * 1024 + j * 32 + lrow];
  const float bv1 = bias[wv * 1024 + j * 32 + 16 + lrow];
  #pragma unroll
  for (int m = 0; m < 4; m++)
    #pragma unroll
    for (int r4 = 0; r4 < 4; r4++){
      int row = m * 16 + lq * 4 + r4;
      G[wv * 2304 + row * 36 + lrow]      = acc[m][0][r4] + bv0;
      G[wv * 2304 + row * 36 + 16 + lrow] = acc[m][1][r4] + bv1;
    }
  __syncthreads();

  const int row = tid >> 2, c0 = (tid & 3) * 8;
  const int base = row * 36 + c0;
  f32x4 gr0 = *(const f32x4*)(G + base),        gr1 = *(const f32x4*)(G + base + 4);
  f32x4 gz0 = *(const f32x4*)(G + 2304 + base), gz1 = *(const f32x4*)(G + 2304 + base + 4);
  f32x4 gi0 = *(const f32x4*)(G + 4608 + base), gi1 = *(const f32x4*)(G + 4608 + base + 4);
  f32x4 gh0 = *(const f32x4*)(G + 6912 + base), gh1 = *(const f32x4*)(G + 6912 + base + 4);
  const int grow = rb * 64 + row;
  const int gcol = j * 32 + c0;
  const f32x4* hp = (const f32x4*)(hws + grow * 1024 + gcol);
  f32x4 h0 = hp[0], h1 = hp[1];
  f32x4 o0, o1; u16x8 hb;
  #pragma unroll
  for (int hv = 0; hv < 2; hv++){
    f32x4 vr = hv ? gr1 : gr0, vz = hv ? gz1 : gz0;
    f32x4 vi = hv ? gi1 : gi0, vh = hv ? gh1 : gh0, vo = hv ? h1 : h0;
    f32x4 vout;
    #pragma unroll
    for (int e = 0; e < 4; e++){
      float rr = 1.f / (1.f + __expf(-vr[e]));
      float zz = 1.f / (1.f + __expf(-vz[e]));
      float x  = vi[e] + rr * vh[e];
      float ex = __expf(-2.f * x);
      float nn = (1.f - ex) / (1.f + ex);
      float hn = nn + zz * (vo[e] - nn);
      vout[e] = hn;
      hb[hv * 4 + e] = f2bf(hn);
    }
    if (hv) o1 = vout; else o0 = vout;
  }
  float* op = out + (size_t)grow * 65536 + (size_t)t * 1024 + gcol;
  ((f32x4*)op)[0] = o0;
  ((f32x4*)op)[1] = o1;
  f32x4* hq = (f32x4*)(hws + grow * 1024 + gcol);
  hq[0] = o0; hq[1] = o1;
  int aaddr = grow * 2048 + ((gcol * 2) ^ ((grow & 7) << 4));
  *(u16x8*)(Anext + aaddr) = hb;
}

// ---------------------------------------------------------------------------
extern "C" void kernel_launch(void* const* d_in, const int* in_sizes, int n_in,
                              void* d_out, int out_size, void* d_ws, size_t ws_size,
                              hipStream_t stream){
  const float* hidden = (const float*)d_in[0];
  const float* wih    = (const float*)d_in[1];
  const float* whh    = (const float*)d_in[2];
  const float* bih    = (const float*)d_in[3];
  const float* bhh    = (const float*)d_in[4];
  char*  ws   = (char*)d_ws;
  char*  WB   = ws;                                   // 8 MB swizzled bf16 weights
  float* bias = (float*)(ws + 8388608);               // 16 KB combined biases
  float* hws  = (float*)(ws + 8388608 + 16384);       // 2 MB fp32 h
  char*  A0   = ws + 8388608 + 16384 + 2097152;       // 1 MB swizzled bf16 h
  char*  A1   = A0 + 1048576;                         // 1 MB (ping-pong)
  float* out  = (float*)d_out;

  hipLaunchKernelGGL(gru_weights, dim3(2048), dim3(256), 0, stream, wih, whh, WB);
  hipLaunchKernelGGL(gru_init,    dim3(256),  dim3(256), 0, stream,
                     hidden, bih, bhh, hws, A0, bias);
  for (int t = 0; t < 64; t++){
    char* Asrc = (t & 1) ? A1 : A0;
    char* Adst = (t & 1) ? A0 : A1;
    hipLaunchKernelGGL(gru_step, dim3(256), dim3(256), 0, stream,
                       (const char*)Asrc, Adst, hws,
                       (const char*)WB, (const float*)bias, out, t);
  }
}